// Round 4
// baseline (557.662 us; speedup 1.0000x reference)
//
#include <hip/hip_runtime.h>

// Problem constants (match reference)
#define NN 500000          // nodes
#define FF 128             // feature dim
#define EE 4000000         // edges
#define BB 4               // graphs
#define GG 32              // voxels per dim
#define VV (BB * GG * GG * GG)   // 131072 voxel slots

// d_out layout (flat float32, reference return order)
#define OUT_X    0
#define OUT_POS  (VV * FF)                 // 16,777,216
#define OUT_EIDX (OUT_POS + VV * 3)        // 17,170,432
#define OUT_ATTR (OUT_EIDX + 2 * EE)       // 25,170,432
#define OUT_MASK (OUT_ATTR + 3 * EE)       // 37,170,432

// ---------------------------------------------------------------------------
// Per-node: voxel id + histogram. 4 nodes/thread, vectorized loads/stores.
// ---------------------------------------------------------------------------
__global__ __launch_bounds__(256) void vid_kernel(
    const float4* __restrict__ posv, const int4* __restrict__ batch4,
    int4* __restrict__ vid4, unsigned int* __restrict__ cnt)
{
    int q = blockIdx.x * 256 + threadIdx.x;        // quad index
    if (q >= NN / 4) return;
    float4 p0 = posv[3 * q], p1 = posv[3 * q + 1], p2 = posv[3 * q + 2];
    int4 b = batch4[q];
    auto vox = [](float px, float py, float pz, int bb) {
        int vx = min(max((int)floorf(px * 0.125f), 0), GG - 1);
        int vy = min(max((int)floorf(py * 0.125f), 0), GG - 1);
        int vz = min(max((int)floorf(pz * 0.125f), 0), GG - 1);
        return bb * (GG * GG * GG) + vx * (GG * GG) + vy * GG + vz;
    };
    int v0 = vox(p0.x, p0.y, p0.z, b.x);
    int v1 = vox(p0.w, p1.x, p1.y, b.y);
    int v2 = vox(p1.z, p1.w, p2.x, b.z);
    int v3 = vox(p2.y, p2.z, p2.w, b.w);
    vid4[q] = make_int4(v0, v1, v2, v3);
    atomicAdd(&cnt[v0], 1u);
    atomicAdd(&cnt[v1], 1u);
    atomicAdd(&cnt[v2], 1u);
    atomicAdd(&cnt[v3], 1u);
}

// ---------------------------------------------------------------------------
// Scan pass 1: per-block exclusive scan of cnt -> offs_local + block sums.
// ---------------------------------------------------------------------------
__global__ __launch_bounds__(256) void scan_local_kernel(
    const unsigned int* __restrict__ cnt, unsigned int* __restrict__ offs,
    unsigned int* __restrict__ bsum)
{
    __shared__ unsigned int s[256];
    int i = blockIdx.x * 256 + threadIdx.x;
    unsigned int val = cnt[i];
    s[threadIdx.x] = val;
    __syncthreads();
    for (int d = 1; d < 256; d <<= 1) {
        unsigned int t = (threadIdx.x >= d) ? s[threadIdx.x - d] : 0u;
        __syncthreads();
        s[threadIdx.x] += t;
        __syncthreads();
    }
    offs[i] = s[threadIdx.x] - val;              // exclusive
    if (threadIdx.x == 255) bsum[blockIdx.x] = s[255];
}

// ---------------------------------------------------------------------------
// Scan pass 2 (fused): each block redundantly reduces bsum[0..bid) (<=512
// L2-hot loads), then emits cursor + packed (offs,cnt) meta. Replaces the
// separate bsum-scan + add kernels (one fewer launch).
// ---------------------------------------------------------------------------
__global__ __launch_bounds__(256) void scan_fuse_kernel(
    const unsigned int* __restrict__ offs_local, const unsigned int* __restrict__ bsum,
    const unsigned int* __restrict__ cnt,
    unsigned int* __restrict__ cursor, uint2* __restrict__ meta)
{
    __shared__ unsigned int red[4];
    int t = threadIdx.x;
    unsigned int partial = 0;
    for (int i = t; i < blockIdx.x; i += 256) partial += bsum[i];
    for (int d = 1; d < 64; d <<= 1) partial += __shfl_xor(partial, d);
    if ((t & 63) == 0) red[t >> 6] = partial;
    __syncthreads();
    unsigned int prefix = red[0] + red[1] + red[2] + red[3];
    int i = blockIdx.x * 256 + t;
    unsigned int o = offs_local[i] + prefix;
    cursor[i] = o;
    meta[i] = make_uint2(o, cnt[i]);
}

// ---------------------------------------------------------------------------
// Scatter node ids into CSR order. 4 nodes/thread (int4 vid load).
// ---------------------------------------------------------------------------
__global__ __launch_bounds__(256) void scatter_kernel(
    const int4* __restrict__ vid4, unsigned int* __restrict__ cursor,
    unsigned int* __restrict__ order)
{
    int q = blockIdx.x * 256 + threadIdx.x;
    if (q >= NN / 4) return;
    int4 v = vid4[q];
    unsigned int n = 4u * (unsigned int)q;
    order[atomicAdd(&cursor[v.x], 1u)] = n;
    order[atomicAdd(&cursor[v.y], 1u)] = n + 1;
    order[atomicAdd(&cursor[v.z], 1u)] = n + 2;
    order[atomicAdd(&cursor[v.w], 1u)] = n + 3;
}

// ---------------------------------------------------------------------------
// One wave per voxel, quarter-split (4 groups x 16 lanes, 4 rows in flight).
// After the pos butterfly (ALL lanes hold the totals), each active lane
// writes its node's record {mean_pos.xyz, (float)vid} -> node_rec[n], giving
// edge_kernel a single 16B gather per endpoint.
// Writes every voxel exactly once (0 for empty) — no memset, no atomics.
// ---------------------------------------------------------------------------
__global__ __launch_bounds__(256) void pool_kernel(
    const float* __restrict__ x, const float* __restrict__ pos,
    const unsigned int* __restrict__ order, const uint2* __restrict__ meta,
    float* __restrict__ out_x, float* __restrict__ out_pos,
    float4* __restrict__ node_rec)
{
    int w = threadIdx.x >> 6;          // wave index in block
    int lane = threadIdx.x & 63;
    int g = lane >> 4;                 // group 0..3 (node subset k ≡ g mod 4)
    int fl = lane & 15;                // float4 chunk within group's row halves
    int v = blockIdx.x * 4 + w;
    uint2 mt = meta[v];
    unsigned int start = mt.x;
    unsigned int c = mt.y;

    float4 mlo = make_float4(-INFINITY, -INFINITY, -INFINITY, -INFINITY);
    float4 mhi = mlo;
    float sx = 0.0f, sy = 0.0f, sz = 0.0f;
    unsigned int my_idx = 0u;          // this lane's node (valid when lane < c, c<=64)

    for (unsigned int base = 0; base < c; base += 64) {
        unsigned int rem = min(c - base, 64u);
        unsigned int idx = (lane < rem) ? order[start + base + lane] : 0u;
        my_idx = idx;
        if (lane < rem) {
            const float* pp = pos + 3 * (size_t)idx;
            sx += pp[0]; sy += pp[1]; sz += pp[2];
        }
        for (unsigned int k = (unsigned int)g; k < rem; k += 4) {
            unsigned int n = __shfl(idx, (int)k);
            const float4* row = (const float4*)(x + (size_t)n * FF);
            float4 a = row[fl];
            float4 b = row[fl + 16];
            mlo.x = fmaxf(mlo.x, a.x); mlo.y = fmaxf(mlo.y, a.y);
            mlo.z = fmaxf(mlo.z, a.z); mlo.w = fmaxf(mlo.w, a.w);
            mhi.x = fmaxf(mhi.x, b.x); mhi.y = fmaxf(mhi.y, b.y);
            mhi.z = fmaxf(mhi.z, b.z); mhi.w = fmaxf(mhi.w, b.w);
        }
    }

    // merge the 4 groups (lanes l, l^16, l^32, l^48 share the same fl)
    #define MERGE(f) f = fmaxf(f, __shfl_xor(f, 16)); f = fmaxf(f, __shfl_xor(f, 32));
    MERGE(mlo.x) MERGE(mlo.y) MERGE(mlo.z) MERGE(mlo.w)
    MERGE(mhi.x) MERGE(mhi.y) MERGE(mhi.z) MERGE(mhi.w)
    #undef MERGE

    float4 res = (lane < 16) ? mlo : mhi;
    if (c == 0) res = make_float4(0.0f, 0.0f, 0.0f, 0.0f);
    if (lane < 32)
        ((float4*)(out_x + (size_t)v * FF))[lane] = res;

    // pos butterfly: every lane ends with the full sums
    for (int d = 1; d < 64; d <<= 1) {
        sx += __shfl_xor(sx, d);
        sy += __shfl_xor(sy, d);
        sz += __shfl_xor(sz, d);
    }
    float inv = 1.0f / fmaxf((float)c, 1.0f);
    float mx = sx * inv, my = sy * inv, mz = sz * inv;
    if (lane == 0) {
        out_pos[3 * v + 0] = mx;
        out_pos[3 * v + 1] = my;
        out_pos[3 * v + 2] = mz;
    }
    float4 recv = make_float4(mx, my, mz, (float)v);
    if (c <= 64) {
        if (lane < (int)c) node_rec[my_idx] = recv;
    } else {
        for (unsigned int base = 0; base < c; base += 64) {
            unsigned int rem = min(c - base, 64u);
            if (lane < rem) node_rec[order[start + base + lane]] = recv;
        }
    }
}

// ---------------------------------------------------------------------------
// Per-edge: 4 edges/thread. ONE float4 gather per endpoint (node_rec carries
// voxel mean pos + vid-as-float). int4 eidx loads, float4 stores; attr staged
// through LDS for fully coalesced writes.
// ---------------------------------------------------------------------------
__global__ __launch_bounds__(256) void edge_kernel(
    const int4* __restrict__ esrc4, const int4* __restrict__ edst4,
    const float4* __restrict__ rec, float* __restrict__ out)
{
    __shared__ float sattr[3072];      // 1024 edges * 3
    int t = threadIdx.x;
    size_t e0 = (size_t)blockIdx.x * 1024;
    int rem = (int)(((size_t)EE - e0 < 1024) ? ((size_t)EE - e0) : 1024);
    size_t q = e0 / 4 + t;             // quad index
    if (4 * t < rem) {
        int4 s = esrc4[q];
        int4 d = edst4[q];
        float4 rs0 = rec[s.x], rs1 = rec[s.y], rs2 = rec[s.z], rs3 = rec[s.w];
        float4 rd0 = rec[d.x], rd1 = rec[d.y], rd2 = rec[d.z], rd3 = rec[d.w];
        bool m0 = (rs0.w != rd0.w), m1 = (rs1.w != rd1.w);
        bool m2 = (rs2.w != rd2.w), m3 = (rs3.w != rd3.w);
        ((float4*)(out + OUT_EIDX))[q]      = make_float4(rs0.w, rs1.w, rs2.w, rs3.w);
        ((float4*)(out + OUT_EIDX + EE))[q] = make_float4(rd0.w, rd1.w, rd2.w, rd3.w);
        ((float4*)(out + OUT_MASK))[q]      = make_float4(m0 ? 1.f : 0.f, m1 ? 1.f : 0.f,
                                                          m2 ? 1.f : 0.f, m3 ? 1.f : 0.f);
        float* sa = sattr + 12 * t;
        sa[0]  = m0 ? (rd0.x - rs0.x) * 0.0625f + 0.5f : 0.f;
        sa[1]  = m0 ? (rd0.y - rs0.y) * 0.0625f + 0.5f : 0.f;
        sa[2]  = m0 ? (rd0.z - rs0.z) * 0.0625f + 0.5f : 0.f;
        sa[3]  = m1 ? (rd1.x - rs1.x) * 0.0625f + 0.5f : 0.f;
        sa[4]  = m1 ? (rd1.y - rs1.y) * 0.0625f + 0.5f : 0.f;
        sa[5]  = m1 ? (rd1.z - rs1.z) * 0.0625f + 0.5f : 0.f;
        sa[6]  = m2 ? (rd2.x - rs2.x) * 0.0625f + 0.5f : 0.f;
        sa[7]  = m2 ? (rd2.y - rs2.y) * 0.0625f + 0.5f : 0.f;
        sa[8]  = m2 ? (rd2.z - rs2.z) * 0.0625f + 0.5f : 0.f;
        sa[9]  = m3 ? (rd3.x - rs3.x) * 0.0625f + 0.5f : 0.f;
        sa[10] = m3 ? (rd3.y - rs3.y) * 0.0625f + 0.5f : 0.f;
        sa[11] = m3 ? (rd3.z - rs3.z) * 0.0625f + 0.5f : 0.f;
    }
    __syncthreads();
    float4* dst = (float4*)(out + OUT_ATTR + 3 * e0);   // 3*e0 % 4 == 0
    const float4* sp = (const float4*)sattr;
    int nf4 = 3 * rem / 4;                              // 768 (or 192 tail)
    for (int i = t; i < nf4; i += 256) dst[i] = sp[i];
}

extern "C" void kernel_launch(void* const* d_in, const int* in_sizes, int n_in,
                              void* d_out, int out_size, void* d_ws, size_t ws_size,
                              hipStream_t stream)
{
    const float* x     = (const float*)d_in[0];
    const float* pos   = (const float*)d_in[1];
    const int*   batch = (const int*)d_in[2];
    const int*   eidx  = (const int*)d_in[3];
    float* out = (float*)d_out;

    // workspace layout (bytes):
    char* ws = (char*)d_ws;
    unsigned int* cnt      = (unsigned int*)(ws + 0);              // VV*4   = 524288
    int*          vid      = (int*)(ws + 524288);                  // NN*4   -> 2524288
    unsigned int* offs     = (unsigned int*)(ws + 2524288);        // VV*4   -> 3048576
    unsigned int* cursor   = (unsigned int*)(ws + 3048576);        // VV*4   -> 3572864
    unsigned int* bsum     = (unsigned int*)(ws + 3572864);        // 512*4  -> 3574912
    unsigned int* order    = (unsigned int*)(ws + 3574912);        // NN*4   -> 5574912
    uint2*        meta     = (uint2*)(ws + 5574912);               // VV*8   -> 6623488
    float4*       node_rec = (float4*)(ws + 6623488);              // NN*16  -> 14623488

    // zero cnt only (512 KB)
    hipMemsetAsync(d_ws, 0, 524288, stream);

    vid_kernel<<<(NN / 4 + 255) / 256, 256, 0, stream>>>(
        (const float4*)pos, (const int4*)batch, (int4*)vid, cnt);
    scan_local_kernel<<<VV / 256, 256, 0, stream>>>(cnt, offs, bsum);
    scan_fuse_kernel<<<VV / 256, 256, 0, stream>>>(offs, bsum, cnt, cursor, meta);
    scatter_kernel<<<(NN / 4 + 255) / 256, 256, 0, stream>>>(
        (const int4*)vid, cursor, order);
    pool_kernel<<<VV / 4, 256, 0, stream>>>(x, pos, order, meta,
                                            out + OUT_X, out + OUT_POS, node_rec);
    edge_kernel<<<(EE + 1023) / 1024, 256, 0, stream>>>(
        (const int4*)eidx, (const int4*)(eidx + EE), node_rec, out);
}